// Round 1
// 246.410 us; speedup vs baseline: 1.0012x; 1.0012x over previous
//
#include <hip/hip_runtime.h>
#include <math.h>

// B=4, S=1024, D=768, H=12, E=64, 3D=2304
// Workspace layout (bytes), total ~137 MB:
//   scbuf fp16 scores -> fp16 probs in place : 100,663,296 @ 0
//     NEW layout: [b][q][h][k] head-minor (head stride 1024 u16 = 2 KB,
//     q stride 12*1024, b stride 12*1024*1024) — avoids 2 MiB power-of-two
//     head-plane stride that aliased HBM channels in k_mix.
//   qkf  fp16 [4096][1536] (Q,K)  : 12,582,912 @ 100,663,296
//   vbuf fp16 [4096][768]  (V)    :  6,291,456 @ 113,246,208
//   ctx  fp16 [4096][768]         :  6,291,456 @ 119,537,664
//   x_h  fp16 :  6,291,456 @ 125,829,120
//   wq_h fp16 :  3,538,944 @ 132,120,576
//   wp_h fp16 :  1,179,648 @ 135,659,520

typedef _Float16 f16;
typedef __attribute__((ext_vector_type(8))) _Float16 f16x8;
typedef __attribute__((ext_vector_type(2))) _Float16 f16x2;
typedef __attribute__((ext_vector_type(4))) float f32x4;
typedef __attribute__((ext_vector_type(2))) float f32x2;
typedef unsigned short u16;

__device__ __forceinline__ u16 f2h(float f) {      // RTN convert
  f16 h = (f16)f;
  return __builtin_bit_cast(u16, h);
}
__device__ __forceinline__ unsigned pk2h(float a, float b) {
  return __builtin_bit_cast(unsigned, __builtin_amdgcn_cvt_pkrtz(a, b));
}

__device__ __forceinline__ void async16(const void* g, void* l) {
  __builtin_amdgcn_global_load_lds(
      (const __attribute__((address_space(1))) unsigned int*)g,
      (__attribute__((address_space(3))) unsigned int*)l, 16, 0, 0);
}

#define MFMA_F16(a, b, c) __builtin_amdgcn_mfma_f32_16x16x32_f16((a), (b), (c), 0, 0, 0)

// ---------------- prep: cast x, Wqkv, Wp to fp16 ----------------
__global__ __launch_bounds__(256) void k_prep(const float* __restrict__ x,
                                              const float* __restrict__ Wqkv,
                                              const float* __restrict__ Wp,
                                              u16* __restrict__ xh,
                                              u16* __restrict__ wh,
                                              u16* __restrict__ wph) {
  const int blk = blockIdx.x, t = threadIdx.x;
  if (blk < 3072) {
    int i = blk * 256 + t;
    float4 v = ((const float4*)x)[i];
    ((ushort4*)xh)[i] = make_ushort4(f2h(v.x), f2h(v.y), f2h(v.z), f2h(v.w));
  } else if (blk < 4800) {
    int i = (blk - 3072) * 256 + t;
    float4 v = ((const float4*)Wqkv)[i];
    ((ushort4*)wh)[i] = make_ushort4(f2h(v.x), f2h(v.y), f2h(v.z), f2h(v.w));
  } else {
    int i = (blk - 4800) * 256 + t;
    float4 v = ((const float4*)Wp)[i];
    ((ushort4*)wph)[i] = make_ushort4(f2h(v.x), f2h(v.y), f2h(v.z), f2h(v.w));
  }
}

// ---------------- K1: qkv = x @ Wqkv^T, fp16 single-MFMA ----------------
// M=4096 N=2304 K=768; 1-D grid 576 with GROUP_M=8 swizzle.
// Q,K cols -> qkf[4096][1536]; V cols (n0>=1536) -> vbuf[4096][768].
__global__ __launch_bounds__(256) void k_qkv(const u16* __restrict__ Axh,
                                             const u16* __restrict__ Bwh,
                                             u16* __restrict__ qkf,
                                             u16* __restrict__ vbuf) {
  __shared__ u16 smem[16384];   // 32 KB: [0:4096)=As, [4096:8192)=Bs; whole = repack T
  u16* As = smem;
  u16* Bs = smem + 4096;
  const int t = threadIdx.x, lane = t & 63, wave = t >> 6;
  const int wm = wave >> 1, wn = wave & 1;
  const int quad = lane >> 4, l16 = lane & 15;
  // GROUP_M=8 swizzle: per-XCD one A-strip reused over all 18 n-blocks
  const int pid = blockIdx.x;
  const int group = pid / 144;              // 144 = 8 * 18
  const int rem = pid - group * 144;
  const int m0 = (group * 8 + (rem & 7)) * 128;
  const int n0 = (rem >> 3) * 128;
  const bool vblk = (n0 >= 1536);
  const int srow = t >> 2, sch = (t & 3) * 8;
  f32x4 acc[4][4];
#pragma unroll
  for (int i = 0; i < 4; ++i)
#pragma unroll
    for (int j = 0; j < 4; ++j) acc[i][j] = (f32x4){0.f, 0.f, 0.f, 0.f};
  for (int k0 = 0; k0 < 768; k0 += 32) {
    const size_t ga = (size_t)(m0 + srow) * 768 + k0 + sch;
    const size_t gb = (size_t)(n0 + srow) * 768 + k0 + sch;
    __syncthreads();
    async16(Axh + ga, &As[t * 8]);
    async16(Axh + ga + (size_t)64 * 768, &As[2048 + t * 8]);
    async16(Bwh + gb, &Bs[t * 8]);
    async16(Bwh + gb + (size_t)64 * 768, &Bs[2048 + t * 8]);
    __syncthreads();
    f16x8 af[4], bfr[4];
#pragma unroll
    for (int i = 0; i < 4; ++i) af[i] = *(const f16x8*)&As[(wm * 64 + i * 16 + l16) * 32 + quad * 8];
#pragma unroll
    for (int j = 0; j < 4; ++j) bfr[j] = *(const f16x8*)&Bs[(wn * 64 + j * 16 + l16) * 32 + quad * 8];
#pragma unroll
    for (int i = 0; i < 4; ++i)
#pragma unroll
      for (int j = 0; j < 4; ++j) acc[i][j] = MFMA_F16(af[i], bfr[j], acc[i][j]);
  }
  // epilogue: XOR-swizzled LDS repack (writes conflict-free), coalesced 16B stores
  __syncthreads();
  u16* T = smem;
#pragma unroll
  for (int i = 0; i < 4; ++i)
#pragma unroll
    for (int j = 0; j < 4; ++j)
#pragma unroll
      for (int r = 0; r < 4; ++r) {
        const int row = wm * 64 + i * 16 + quad * 4 + r;
        const int col = wn * 64 + j * 16 + l16;
        T[row * 128 + (col ^ ((row & 7) << 4))] = f2h(acc[i][j][r]);
      }
  __syncthreads();
  const int row = t >> 1, halfc = (t & 1) * 64;
  const int sw = (row & 7) << 4;
  u16* dst = vblk ? (vbuf + (size_t)(m0 + row) * 768 + (n0 - 1536) + halfc)
                  : (qkf + (size_t)(m0 + row) * 1536 + n0 + halfc);
#pragma unroll
  for (int c = 0; c < 64; c += 8)
    *(uint4*)(dst + c) = *(const uint4*)&T[row * 128 + ((halfc + c) ^ sw)];
}

// ---------------- K2: scores(fp16) = Q @ K^T per (b,h), single fp16 MFMA ----------------
// Output now head-minor: scbuf[((b*1024+q)*12 + h)*1024 + k]
__global__ __launch_bounds__(256) void k_qk(const u16* __restrict__ qkf,
                                            u16* __restrict__ scbuf) {
  __shared__ u16 smem[4][4096];   // [0]=A stage, [1]=B stage; all 4 = repack tile
  u16* As = smem[0]; u16* Bs = smem[1];
  const int t = threadIdx.x, lane = t & 63, wave = t >> 6;
  const int wm = wave >> 1, wn = wave & 1;
  const int quad = lane >> 4, l16 = lane & 15;
  const int bh = blockIdx.z, b = bh / 12, h = bh % 12;
  const int m0 = blockIdx.y * 128, n0 = blockIdx.x * 128;
  const int srow = t >> 2, sch = (t & 3) * 8;
  f32x4 acc[4][4];
#pragma unroll
  for (int i = 0; i < 4; ++i)
#pragma unroll
    for (int j = 0; j < 4; ++j) acc[i][j] = (f32x4){0.f, 0.f, 0.f, 0.f};
  for (int k0 = 0; k0 < 64; k0 += 32) {
    const size_t ga = (size_t)(b * 1024 + m0 + srow) * 1536 + h * 64 + k0 + sch;
    const size_t gb = (size_t)(b * 1024 + n0 + srow) * 1536 + 768 + h * 64 + k0 + sch;
    __syncthreads();
    async16(qkf + ga, &As[t * 8]);
    async16(qkf + ga + (size_t)64 * 1536, &As[2048 + t * 8]);
    async16(qkf + gb, &Bs[t * 8]);
    async16(qkf + gb + (size_t)64 * 1536, &Bs[2048 + t * 8]);
    __syncthreads();
    f16x8 af[4], bfr[4];
#pragma unroll
    for (int i = 0; i < 4; ++i) af[i] = *(const f16x8*)&As[(wm * 64 + i * 16 + l16) * 32 + quad * 8];
#pragma unroll
    for (int j = 0; j < 4; ++j) bfr[j] = *(const f16x8*)&Bs[(wn * 64 + j * 16 + l16) * 32 + quad * 8];
#pragma unroll
    for (int i = 0; i < 4; ++i)
#pragma unroll
      for (int j = 0; j < 4; ++j) acc[i][j] = MFMA_F16(af[i], bfr[j], acc[i][j]);
  }
  __syncthreads();
  u16* T = &smem[0][0];
#pragma unroll
  for (int i = 0; i < 4; ++i)
#pragma unroll
    for (int j = 0; j < 4; ++j)
#pragma unroll
      for (int r = 0; r < 4; ++r) {
        const int row = wm * 64 + i * 16 + quad * 4 + r;
        const int col = wn * 64 + j * 16 + l16;
        T[row * 128 + (col ^ ((row & 7) << 4))] = f2h(acc[i][j][r]);
      }
  __syncthreads();
  const int row = t >> 1, halfc = (t & 1) * 64;
  const int sw = (row & 7) << 4;
  // head-minor store: q-stride = 12*1024 elems, head offset h*1024
  u16* dst = scbuf + ((size_t)(b * 1024 + m0 + row) * 12 + h) * 1024 + n0 + halfc;
#pragma unroll
  for (int c = 0; c < 64; c += 8)
    *(uint4*)(dst + c) = *(const uint4*)&T[row * 128 + ((halfc + c) ^ sw)];
}

// ---------------- K3: mix1 -> constant-shift softmax -> mix2; fp16 in/out, in place ----------------
// Head-minor layout: each block streams one contiguous 24 KB (b,q) slab.
__global__ __launch_bounds__(256) void k_mix(u16* __restrict__ scbuf,
                                             const float* __restrict__ Wl,
                                             const float* __restrict__ bl,
                                             const float* __restrict__ Ww,
                                             const float* __restrict__ bw) {
  __shared__ float wl_s[144], ww_s[144], bl_s[12], bw_s[12];
  __shared__ float red[4][12];
  const int t = threadIdx.x, lane = t & 63, wave = t >> 6;
  const int bq = blockIdx.x, b = bq >> 10, q = bq & 1023;
  if (t < 144) { wl_s[t] = Wl[t]; ww_s[t] = Ww[t]; }
  if (t < 12)  { bl_s[t] = bl[t]; bw_s[t] = bw[t]; }
  // contiguous slab base: (b*1024+q)*12*1024, per-thread column offset 4*t
  const size_t rowbase = ((size_t)(b * 1024 + q) * 12) * 1024 + 4 * t;  // + h<<10
  f32x2 raw[12][2];
#pragma unroll
  for (int h = 0; h < 12; ++h) {
    const u16* p = scbuf + rowbase + ((size_t)h << 10);
    uint2 u = *(const uint2*)p;
    f16x2 a01 = __builtin_bit_cast(f16x2, u.x);
    f16x2 a23 = __builtin_bit_cast(f16x2, u.y);
    raw[h][0] = (f32x2){(float)a01.x, (float)a01.y};
    raw[h][1] = (f32x2){(float)a23.x, (float)a23.y};
  }
  __syncthreads();
  // mix1 (pk-fma), bias pre-shifted by -16 (constant-shift softmax)
  f32x2 lg[12][2];
#pragma unroll
  for (int g = 0; g < 12; ++g) {
    f32x2 a0 = {bl_s[g] - 16.f, bl_s[g] - 16.f}, a1 = a0;
#pragma unroll
    for (int h = 0; h < 12; ++h) {
      const float wv = wl_s[g * 12 + h];
      const f32x2 w = {wv, wv};
      a0 = __builtin_elementwise_fma(w, raw[h][0], a0);
      a1 = __builtin_elementwise_fma(w, raw[h][1], a1);
    }
    lg[g][0] = a0; lg[g][1] = a1;
  }
  // exp + row sum (no max pass: exp(l-16) safe, |logit| << 104)
  float sm[12];
#pragma unroll
  for (int g = 0; g < 12; ++g) {
    f32x2 e0, e1;
    e0.x = __expf(lg[g][0].x); e0.y = __expf(lg[g][0].y);
    e1.x = __expf(lg[g][1].x); e1.y = __expf(lg[g][1].y);
    lg[g][0] = e0; lg[g][1] = e1;
    f32x2 s2 = e0 + e1;
    sm[g] = s2.x + s2.y;
  }
#pragma unroll
  for (int off = 32; off > 0; off >>= 1)
#pragma unroll
    for (int g = 0; g < 12; ++g) sm[g] += __shfl_xor(sm[g], off);
  if (lane == 0) {
#pragma unroll
    for (int g = 0; g < 12; ++g) red[wave][g] = sm[g];
  }
  __syncthreads();
#pragma unroll
  for (int g = 0; g < 12; ++g) {
    const float inv = 1.0f / (red[0][g] + red[1][g] + red[2][g] + red[3][g]);
    const f32x2 iv = {inv, inv};
    lg[g][0] *= iv;
    lg[g][1] *= iv;
  }
  // mix2 (pk-fma) + fp16 pack stores, in place
#pragma unroll
  for (int g2 = 0; g2 < 12; ++g2) {
    f32x2 o0 = {bw_s[g2], bw_s[g2]}, o1 = o0;
#pragma unroll
    for (int h = 0; h < 12; ++h) {
      const float wv = ww_s[g2 * 12 + h];
      const f32x2 w = {wv, wv};
      o0 = __builtin_elementwise_fma(w, lg[h][0], o0);
      o1 = __builtin_elementwise_fma(w, lg[h][1], o1);
    }
    uint2 st = make_uint2(pk2h(o0.x, o0.y), pk2h(o1.x, o1.y));
    *(uint2*)(scbuf + rowbase + ((size_t)g2 << 10)) = st;
  }
}

// ---------------- K4: ctx = P(fp16) @ V(fp16) per (b,h); V transposed in-LDS ----------------
// M=1024 N=64 K=1024; BM=128; waves 2x2, each 64x32 (4x2 frags)
// P now read from head-minor layout.
__global__ __launch_bounds__(256) void k_pv(const u16* __restrict__ probs,
                                            const u16* __restrict__ vbuf,
                                            u16* __restrict__ ctx) {
  __shared__ u16 As[4096];      // 128x32 P tile
  __shared__ u16 Bs[64 * 40];   // V^T tile: [e][s-chunk 32], row stride 40 (16B-aligned)
  const int t = threadIdx.x, lane = t & 63, wave = t >> 6;
  const int wm = wave >> 1, wn = wave & 1;
  const int quad = lane >> 4, l16 = lane & 15;
  const int bh = blockIdx.y, b = bh / 12, h = bh % 12;
  const int m0 = blockIdx.x * 128;
  const int srow = t >> 2, sch = (t & 3) * 8;
  const int ev = t & 63, s8 = (t >> 6) * 8;   // V transpose-load: e=ev, s-chunk s8
  f32x4 acc[4][2];
#pragma unroll
  for (int i = 0; i < 4; ++i)
#pragma unroll
    for (int j = 0; j < 2; ++j) acc[i][j] = (f32x4){0.f, 0.f, 0.f, 0.f};
  for (int k0 = 0; k0 < 1024; k0 += 32) {
    const u16* vp = vbuf + (size_t)(b * 1024 + k0 + s8) * 768 + h * 64 + ev;
    u16 vcol[8];
#pragma unroll
    for (int i = 0; i < 8; ++i) vcol[i] = vp[(size_t)i * 768];
    __syncthreads();
    // head-minor P row: ((b*1024 + q)*12 + h)*1024 + k
    const u16* ga = probs + ((size_t)(b * 1024 + m0 + srow) * 12 + h) * 1024 + k0 + sch;
    async16(ga, &As[t * 8]);
    async16(ga + (size_t)64 * 12 * 1024, &As[2048 + t * 8]);
    *(ushort4*)&Bs[ev * 40 + s8] = make_ushort4(vcol[0], vcol[1], vcol[2], vcol[3]);
    *(ushort4*)&Bs[ev * 40 + s8 + 4] = make_ushort4(vcol[4], vcol[5], vcol[6], vcol[7]);
    __syncthreads();
    f16x8 af[4], bfr[2];
#pragma unroll
    for (int i = 0; i < 4; ++i) af[i] = *(const f16x8*)&As[(wm * 64 + i * 16 + l16) * 32 + quad * 8];
#pragma unroll
    for (int j = 0; j < 2; ++j) bfr[j] = *(const f16x8*)&Bs[(wn * 32 + j * 16 + l16) * 40 + quad * 8];
#pragma unroll
    for (int i = 0; i < 4; ++i)
#pragma unroll
      for (int j = 0; j < 2; ++j) acc[i][j] = MFMA_F16(af[i], bfr[j], acc[i][j]);
  }
#pragma unroll
  for (int i = 0; i < 4; ++i)
#pragma unroll
    for (int j = 0; j < 2; ++j)
#pragma unroll
      for (int r = 0; r < 4; ++r) {
        int q = m0 + wm * 64 + i * 16 + quad * 4 + r;
        int e = wn * 32 + j * 16 + l16;
        ctx[(size_t)(b * 1024 + q) * 768 + h * 64 + e] = f2h(acc[i][j][r]);
      }
}

// ---------------- K5: out = ctx @ Wp^T + bp (fp16 MFMA, fp32 out) ----------------
// M=4096 N=768 K=768
__global__ __launch_bounds__(256) void k_oproj(const u16* __restrict__ A,
                                               const u16* __restrict__ Bm,
                                               const float* __restrict__ bp,
                                               float* __restrict__ out) {
  __shared__ u16 As[4096];
  __shared__ u16 Bs[4096];
  const int t = threadIdx.x, lane = t & 63, wave = t >> 6;
  const int wm = wave >> 1, wn = wave & 1;
  const int quad = lane >> 4, l16 = lane & 15;
  const int m0 = blockIdx.y * 128, n0 = blockIdx.x * 128;
  const int srow = t >> 2, sch = (t & 3) * 8;
  f32x4 acc[4][4];
#pragma unroll
  for (int i = 0; i < 4; ++i)
#pragma unroll
    for (int j = 0; j < 4; ++j) acc[i][j] = (f32x4){0.f, 0.f, 0.f, 0.f};
  for (int k0 = 0; k0 < 768; k0 += 32) {
    __syncthreads();
    const u16* ga = A + (size_t)(m0 + srow) * 768 + k0 + sch;
    const u16* gb = Bm + (size_t)(n0 + srow) * 768 + k0 + sch;
    async16(ga, &As[t * 8]);
    async16(ga + (size_t)64 * 768, &As[2048 + t * 8]);
    async16(gb, &Bs[t * 8]);
    async16(gb + (size_t)64 * 768, &Bs[2048 + t * 8]);
    __syncthreads();
    f16x8 af[4], bfr[4];
#pragma unroll
    for (int i = 0; i < 4; ++i) af[i] = *(const f16x8*)&As[(wm * 64 + i * 16 + l16) * 32 + quad * 8];
#pragma unroll
    for (int j = 0; j < 4; ++j) bfr[j] = *(const f16x8*)&Bs[(wn * 64 + j * 16 + l16) * 32 + quad * 8];
#pragma unroll
    for (int i = 0; i < 4; ++i)
#pragma unroll
      for (int j = 0; j < 4; ++j) acc[i][j] = MFMA_F16(af[i], bfr[j], acc[i][j]);
  }
#pragma unroll
  for (int i = 0; i < 4; ++i)
#pragma unroll
    for (int j = 0; j < 4; ++j)
#pragma unroll
      for (int r = 0; r < 4; ++r) {
        const int row = m0 + wm * 64 + i * 16 + quad * 4 + r;
        const int col = n0 + wn * 64 + j * 16 + l16;
        out[(size_t)row * 768 + col] = acc[i][j][r] + bp[col];
      }
}

extern "C" void kernel_launch(void* const* d_in, const int* in_sizes, int n_in,
                              void* d_out, int out_size, void* d_ws, size_t ws_size,
                              hipStream_t stream) {
  const float* x    = (const float*)d_in[0];
  const float* Wqkv = (const float*)d_in[1];
  const float* Wl   = (const float*)d_in[2];
  const float* bl   = (const float*)d_in[3];
  const float* Ww   = (const float*)d_in[4];
  const float* bw   = (const float*)d_in[5];
  const float* Wp   = (const float*)d_in[6];
  const float* bp   = (const float*)d_in[7];
  float* out = (float*)d_out;

  char* ws = (char*)d_ws;
  u16* scbuf = (u16*)(ws + 0);               // 100,663,296 B, [b][q][h][k]
  u16* qkf   = (u16*)(ws + 100663296ull);    //  12,582,912 B
  u16* vbuf  = (u16*)(ws + 113246208ull);    //   6,291,456 B
  u16* ctx   = (u16*)(ws + 119537664ull);    //   6,291,456 B
  u16* x_h   = (u16*)(ws + 125829120ull);    //   6,291,456 B
  u16* wq_h  = (u16*)(ws + 132120576ull);    //   3,538,944 B
  u16* wp_h  = (u16*)(ws + 135659520ull);    //   1,179,648 B

  hipLaunchKernelGGL(k_prep, dim3(5376), dim3(256), 0, stream,
                     x, Wqkv, Wp, x_h, wq_h, wp_h);
  hipLaunchKernelGGL(k_qkv,  dim3(576),      dim3(256), 0, stream, x_h, wq_h, qkf, vbuf);
  hipLaunchKernelGGL(k_qk,   dim3(8, 8, 48), dim3(256), 0, stream, qkf, scbuf);
  hipLaunchKernelGGL(k_mix,  dim3(4096),     dim3(256), 0, stream, scbuf, Wl, bl, Ww, bw);
  hipLaunchKernelGGL(k_pv,   dim3(8, 48),    dim3(256), 0, stream, scbuf, vbuf, ctx);
  hipLaunchKernelGGL(k_oproj, dim3(6, 32),   dim3(256), 0, stream, ctx, wp_h, bp, out);
}